// Round 11
// baseline (22894.452 us; speedup 1.0000x reference)
//
#include <hip/hip_runtime.h>
#include <hip/hip_bf16.h>

// NCDE branch: B=128, L=200 RK4(3/8), C=32, H=128, M=256.
// 16 clusters x 8 rows; 32 blocks/cluster; grid 512, block 256 (2 blocks/CU).
// G1 (z@W1) is REPLICATED per block (W1 streamed from L2) so the only
// cross-block dependency is the k-vector -> ONE cluster barrier per stage.
// k1 is step-parity double-buffered to close the z-update/next-k1 race.

#define AGENT __HIP_MEMORY_SCOPE_AGENT

__device__ __forceinline__ void stA(float* p, float v) {
  __hip_atomic_store(p, v, __ATOMIC_RELAXED, AGENT);
}
__device__ __forceinline__ float4 ld4A(const float* p) {
  float4 a;
  asm volatile("global_load_dwordx4 %0, %1, off sc0 sc1\n\t"
               "s_waitcnt vmcnt(0)"
               : "=v"(a) : "v"(p) : "memory");
  return a;
}
__device__ __forceinline__ void ld4A2(const float* p0, const float* p1,
                                      float4& a, float4& b) {
  asm volatile("global_load_dwordx4 %0, %2, off sc0 sc1\n\t"
               "global_load_dwordx4 %1, %3, off sc0 sc1\n\t"
               "s_waitcnt vmcnt(0)"
               : "=&v"(a), "=&v"(b) : "v"(p0), "v"(p1) : "memory");
}

__global__ void __launch_bounds__(256) ncde_kernel(
    const float* __restrict__ coeffs, const float* __restrict__ W1,
    const float* __restrict__ b1, const float* __restrict__ W2,
    const float* __restrict__ b2, const float* __restrict__ Wz,
    const float* __restrict__ bz, const float* __restrict__ gam,
    const float* __restrict__ bet, float* __restrict__ out,
    float* __restrict__ ws)
{
  __shared__ float zs[8][136];     // zin rows, padded (544B row: bank-skewed)
  __shared__ float pacc[8192];     // G1 partials [4][2048] / G2 partials [8][1024]
  __shared__ float hs[2048];       // h [8][256]
  __shared__ float dsv[8][32];
  __shared__ float psum[8][32];
  __shared__ float kout[8][4];
  __shared__ float lnsum[8][32], lnsq[8][32], lnmv[8][2];

  const int t  = threadIdx.x;
  const int cl = blockIdx.x >> 5;   // 0..15; cl and cl+8 co-resident per CU
  const int jp = blockIdx.x & 31;   // same-jp blocks land on one XCD (32%8==0)

  unsigned* slots = (unsigned*)ws + cl * 64;   // 16 x 64 u32 (memset to 0)
  unsigned* genp  = slots + 32;
  unsigned  ph = 0;

  // k buffers per cluster: [5][8][128]; buf0/1 = k1 parity, 2..4 = k2..k4
  float* kbc = ws + 1024 + cl * 5120;

  const int zrow = t >> 5;   // 0..7 owned row
  const int zseg = t & 31;   // 4-float segment
  const int brow = cl * 8 + zrow;

  const float  b1v = b1[t];                                   // m = t
  const float4 b2v = *(const float4*)&b2[jp * 128 + (t & 31) * 4];

  // ---- z0 = a[:,0] @ Wz + bz ----
  float zr_[4];
  {
    const float* arow = coeffs + (size_t)brow * 25600;
    #pragma unroll
    for (int i = 0; i < 4; ++i) {
      int h = zseg * 4 + i;
      float acc = bz[h];
      for (int c = 0; c < 32; ++c) acc += arow[c] * Wz[c * 128 + h];
      zr_[i] = acc;
    }
  }

  // ---- contention-free cluster barrier (flag array + leader ballot) ----
  auto cbar = [&]() {
    __syncthreads();
    asm volatile("s_waitcnt vmcnt(0)" ::: "memory");
    ++ph;
    if (t == 0) __hip_atomic_store(&slots[jp], ph, __ATOMIC_RELAXED, AGENT);
    if (jp == 0) {
      if (t < 32) {
        while (__hip_atomic_load(&slots[t], __ATOMIC_RELAXED, AGENT) < ph)
          __builtin_amdgcn_s_sleep(1);
        if (t == 0) __hip_atomic_store(genp, ph, __ATOMIC_RELAXED, AGENT);
      }
    } else if (t == 0) {
      while (__hip_atomic_load(genp, __ATOMIC_RELAXED, AGENT) < ph)
        __builtin_amdgcn_s_sleep(1);
    }
    __syncthreads();
  };

  auto stage = [&](int l, int s) {
    const int p1 = l & 1;
    // -- phase 1: d vector + zin build --
    {
      int lidx; float f = 0.f; bool bonly = false;
      if (s == 0) { if (l == 0) { lidx = 0; bonly = true; } else { lidx = l - 1; f = 1.f; } }
      else if (s == 1) { lidx = l; f = 1.f / 3.f; }
      else if (s == 2) { lidx = l; f = 2.f / 3.f; }
      else             { lidx = l; f = 1.f; }
      const float* cp = coeffs + (size_t)brow * 25600 + (size_t)lidx * 128;
      float bco = cp[32 + zseg];
      dsv[zrow][zseg] = bonly ? bco : bco + (cp[64 + zseg] + cp[96 + zseg] * f) * f;

      int idx4 = zrow * 128 + zseg * 4;
      float4 zv = make_float4(zr_[0], zr_[1], zr_[2], zr_[3]);
      if (s == 1) {
        float4 k1 = ld4A(kbc + p1 * 1024 + idx4);
        zv.x += (1.f/3.f)*k1.x; zv.y += (1.f/3.f)*k1.y;
        zv.z += (1.f/3.f)*k1.z; zv.w += (1.f/3.f)*k1.w;
      } else if (s == 2) {
        float4 k1, k2; ld4A2(kbc + p1 * 1024 + idx4, kbc + 2 * 1024 + idx4, k1, k2);
        zv.x += k2.x - (1.f/3.f)*k1.x; zv.y += k2.y - (1.f/3.f)*k1.y;
        zv.z += k2.z - (1.f/3.f)*k1.z; zv.w += k2.w - (1.f/3.f)*k1.w;
      } else if (s == 3) {
        float4 k1, k2; ld4A2(kbc + p1 * 1024 + idx4, kbc + 2 * 1024 + idx4, k1, k2);
        float4 k3 = ld4A(kbc + 3 * 1024 + idx4);
        zv.x += k1.x - k2.x + k3.x; zv.y += k1.y - k2.y + k3.y;
        zv.z += k1.z - k2.z + k3.z; zv.w += k1.w - k2.w + k3.w;
      }
      *(float4*)&zs[zrow][zseg * 4] = zv;
    }
    __syncthreads();
    // -- phase 2: G1 full (thread = (cg, kq2): 8 rows x 4 cols x 32-hc slice) --
    {
      const int cg = t & 63, kq2 = t >> 6;
      const float* w1p = W1 + (size_t)(kq2 * 32) * 256 + cg * 4;
      float4 acc[8];
      #pragma unroll
      for (int r = 0; r < 8; ++r) acc[r] = make_float4(0.f, 0.f, 0.f, 0.f);
      float4 n0 = *(const float4*)(w1p);
      float4 n1 = *(const float4*)(w1p + 256);
      float4 n2 = *(const float4*)(w1p + 512);
      float4 n3 = *(const float4*)(w1p + 768);
      for (int mo = 0; mo < 8; ++mo) {
        float4 w0 = n0, w1v = n1, w2v = n2, w3v = n3;
        if (mo < 7) {
          const float* nb = w1p + (size_t)(mo + 1) * 1024;
          n0 = *(const float4*)(nb);
          n1 = *(const float4*)(nb + 256);
          n2 = *(const float4*)(nb + 512);
          n3 = *(const float4*)(nb + 768);
        }
        #pragma unroll
        for (int r = 0; r < 8; ++r) {
          float4 zq = *(const float4*)&zs[r][kq2 * 32 + mo * 4];
          acc[r].x += zq.x * w0.x + zq.y * w1v.x + zq.z * w2v.x + zq.w * w3v.x;
          acc[r].y += zq.x * w0.y + zq.y * w1v.y + zq.z * w2v.y + zq.w * w3v.y;
          acc[r].z += zq.x * w0.z + zq.y * w1v.z + zq.z * w2v.z + zq.w * w3v.z;
          acc[r].w += zq.x * w0.w + zq.y * w1v.w + zq.z * w2v.w + zq.w * w3v.w;
        }
      }
      #pragma unroll
      for (int r = 0; r < 8; ++r)
        *(float4*)&pacc[kq2 * 2048 + r * 256 + cg * 4] = acc[r];
    }
    __syncthreads();
    // -- phase 3: reduce G1 partials + bias + relu -> hs --
    {
      #pragma unroll
      for (int i = 0; i < 8; ++i) {
        int idx = i * 256 + t;
        float v = pacc[idx] + pacc[2048 + idx] + pacc[4096 + idx] + pacc[6144 + idx];
        hs[idx] = fmaxf(v + b1v, 0.f);
      }
    }
    __syncthreads();
    // -- phase 4: G2 (thread = (col4, kq): 8 rows x 4 cols x 32-m slice) --
    {
      const int col4 = t & 31, kq = t >> 5;
      const float* w2b = W2 + (size_t)(kq * 32) * 4096 + jp * 128 + col4 * 4;
      float4 acc[8];
      #pragma unroll
      for (int r = 0; r < 8; ++r) acc[r] = make_float4(0.f, 0.f, 0.f, 0.f);
      float4 n0 = *(const float4*)(w2b);
      float4 n1 = *(const float4*)(w2b + 4096);
      float4 n2 = *(const float4*)(w2b + 2 * 4096);
      float4 n3 = *(const float4*)(w2b + 3 * 4096);
      for (int mo = 0; mo < 8; ++mo) {
        float4 w0 = n0, w1v = n1, w2v = n2, w3v = n3;
        if (mo < 7) {
          const float* nb = w2b + (size_t)(mo + 1) * 4 * 4096;
          n0 = *(const float4*)(nb);
          n1 = *(const float4*)(nb + 4096);
          n2 = *(const float4*)(nb + 2 * 4096);
          n3 = *(const float4*)(nb + 3 * 4096);
        }
        #pragma unroll
        for (int r = 0; r < 8; ++r) {
          float4 h4 = *(const float4*)&hs[r * 256 + (kq * 8 + mo) * 4];
          acc[r].x += h4.x * w0.x + h4.y * w1v.x + h4.z * w2v.x + h4.w * w3v.x;
          acc[r].y += h4.x * w0.y + h4.y * w1v.y + h4.z * w2v.y + h4.w * w3v.y;
          acc[r].z += h4.x * w0.z + h4.y * w1v.z + h4.z * w2v.z + h4.w * w3v.z;
          acc[r].w += h4.x * w0.w + h4.y * w1v.w + h4.z * w2v.w + h4.w * w3v.w;
        }
      }
      #pragma unroll
      for (int r = 0; r < 8; ++r) {
        float* kp = &pacc[kq * 1024 + r * 128 + col4];
        kp[0] = acc[r].x; kp[32] = acc[r].y; kp[64] = acc[r].z; kp[96] = acc[r].w;
      }
    }
    __syncthreads();
    // -- phase 5: reduce G2 partials over kq (vectorized) --
    {
      float4* k4p = (float4*)pacc;
      float4 sv = k4p[t];
      #pragma unroll
      for (int kq = 1; kq < 8; ++kq) {
        float4 v = k4p[kq * 256 + t];
        sv.x += v.x; sv.y += v.y; sv.z += v.z; sv.w += v.w;
      }
      k4p[t] = sv;
    }
    __syncthreads();
    // -- phase 6: bias + tanh + d-weight (thread = (r, g), 4 cols) --
    {
      int r = t >> 5, g = t & 31;
      float pre0 = pacc[r * 128 + 0 * 32 + g] + b2v.x;
      float pre1 = pacc[r * 128 + 1 * 32 + g] + b2v.y;
      float pre2 = pacc[r * 128 + 2 * 32 + g] + b2v.z;
      float pre3 = pacc[r * 128 + 3 * 32 + g] + b2v.w;
      float lsum = 0.f;
      #pragma unroll
      for (int i = 0; i < 4; ++i) {
        float pre = (i == 0) ? pre0 : (i == 1) ? pre1 : (i == 2) ? pre2 : pre3;
        float ax = fabsf(pre);
        float e = __expf(-2.f * ax);
        float th = (1.f - e) * __builtin_amdgcn_rcpf(1.f + e);
        th = (pre < 0.f) ? -th : th;
        lsum += th * dsv[r][(g * 4 + i) & 31];
      }
      psum[r][g] = lsum;
    }
    __syncthreads();
    // -- phase 7: kout reduce + publish k slice --
    if (t < 32) {
      int r = t >> 2, hl = t & 3;
      float s0 = 0.f;
      #pragma unroll
      for (int g = 0; g < 8; ++g) s0 += psum[r][hl * 8 + g];
      kout[r][hl] = s0;
      int buf = (s == 0) ? p1 : (s + 1);
      stA(kbc + buf * 1024 + r * 128 + jp * 4 + hl, s0);
    }
    cbar();
  };

  auto lnorm = [&](int w) {
    {
      float4 v = ld4A(kbc + (w & 1) * 1024 + zrow * 128 + zseg * 4);
      lnsum[zrow][zseg] = v.x + v.y + v.z + v.w;
      lnsq[zrow][zseg]  = v.x*v.x + v.y*v.y + v.z*v.z + v.w*v.w;
    }
    __syncthreads();
    if (t < 8) {
      float s0 = 0.f, q0 = 0.f;
      #pragma unroll
      for (int j = 0; j < 32; ++j) { s0 += lnsum[t][j]; q0 += lnsq[t][j]; }
      float mu = s0 * (1.f / 128.f);
      float var = q0 * (1.f / 128.f) - mu * mu;
      lnmv[t][0] = mu;
      lnmv[t][1] = rsqrtf(var + 1e-5f);
    }
    __syncthreads();
    if (t < 32) {
      int r = t >> 2, hl = t & 3, h = jp * 4 + hl;
      float x = kout[r][hl];
      float y = (x - lnmv[r][0]) * lnmv[r][1] * gam[h] + bet[h];
      y = fminf(fmaxf(y, -1000.f), 1000.f);
      out[(size_t)(cl * 8 + r) * 25728 + (size_t)w * 128 + h] = y;
    }
    __syncthreads();
  };

  for (int l = 0; l < 200; ++l) {
    stage(l, 0);
    lnorm(l);
    stage(l, 1);
    stage(l, 2);
    stage(l, 3);
    {  // z += (k1 + 3(k2+k3) + k4)/8
      int idx4 = zrow * 128 + zseg * 4;
      float4 k1, k2, k3, k4;
      ld4A2(kbc + (l & 1) * 1024 + idx4, kbc + 2 * 1024 + idx4, k1, k2);
      ld4A2(kbc + 3 * 1024 + idx4,       kbc + 4 * 1024 + idx4, k3, k4);
      zr_[0] += 0.125f * (k1.x + 3.f * (k2.x + k3.x) + k4.x);
      zr_[1] += 0.125f * (k1.y + 3.f * (k2.y + k3.y) + k4.y);
      zr_[2] += 0.125f * (k1.z + 3.f * (k2.z + k3.z) + k4.z);
      zr_[3] += 0.125f * (k1.w + 3.f * (k2.w + k3.w) + k4.w);
    }
  }
  stage(200, 0);
  lnorm(200);
}

extern "C" void kernel_launch(void* const* d_in, const int* in_sizes, int n_in,
                              void* d_out, int out_size, void* d_ws, size_t ws_size,
                              hipStream_t stream) {
  (void)in_sizes; (void)n_in; (void)out_size; (void)ws_size;
  const float* coeffs = (const float*)d_in[0];
  const float* W1     = (const float*)d_in[1];
  const float* b1     = (const float*)d_in[2];
  const float* W2     = (const float*)d_in[3];
  const float* b2     = (const float*)d_in[4];
  const float* Wz     = (const float*)d_in[5];
  const float* bz     = (const float*)d_in[6];
  const float* gam    = (const float*)d_in[7];
  const float* bet    = (const float*)d_in[8];
  float* out = (float*)d_out;
  float* ws  = (float*)d_ws;

  // barrier region (16 clusters x 64 u32 = 4096B) must start at 0 each launch
  hipMemsetAsync(d_ws, 0, 4096, stream);
  ncde_kernel<<<dim3(512), dim3(256), 0, stream>>>(coeffs, W1, b1, W2, b2, Wz, bz,
                                                   gam, bet, out, ws);
}